// Round 11
// baseline (191.683 us; speedup 1.0000x reference)
//
#include <hip/hip_runtime.h>

#define N_NODES 100000
#define N_EDGES 800000
#define H 128
#define MAX_Z 1000
#define N_GRAPHS 500
#define ELL_CAP 32
#define SB 782                   // edge scan blocks: ceil(800000/(256*4))
#define SSTRIDE (SB * 256)       // 200192 threads, 4 edges each
#define SCAPC 33                 // 1 center + 32 neighbor rows

typedef __attribute__((ext_vector_type(8))) short bf16x8;
typedef __attribute__((ext_vector_type(4))) float f32x4;

__device__ __forceinline__ unsigned short f2bf(float f) {
    union { float f; unsigned u; } x; x.f = f;
    unsigned r = x.u + 0x7fffu + ((x.u >> 16) & 1u);   // RTNE
    return (unsigned short)(r >> 16);
}
__device__ __forceinline__ float bf2f(unsigned short u) {
    return __uint_as_float((unsigned)u << 16);
}
// packed ELL entry: src | z[src]<<17  (src<2^17, z<2^10; 5 bits spare)
__device__ __forceinline__ int dec_s(unsigned e) {
    int s = (int)(e & 0x1FFFFu);
    return s < N_NODES ? s : 0;          // poison (0xAA..)-safe
}
__device__ __forceinline__ int dec_z(unsigned e) {
    int zz = (int)((e >> 17) & 0x3FFu);
    return zz < MAX_Z ? zz : 0;
}

// ---- k_scan: packed-ELL build (4-edge ILP) + T0 GEMM + W1 pack -----------
// The z[src] gathers are independent loads issued before the returning
// atomics; they hide under the RMW latency that dominates this kernel
// (measured ~40us floor, rounds 5-9). Packing z here deletes ALL z gathers
// from the back half's hot loops.
__global__ __launch_bounds__(256) void k_scan(const int* __restrict__ esrc,
                                              const int* __restrict__ edst,
                                              const int* __restrict__ mask,
                                              const int* __restrict__ z,
                                              int* fill, unsigned* ell,
                                              const float* __restrict__ ztab,
                                              const float* __restrict__ W0,
                                              const float* __restrict__ W1,
                                              unsigned short* Wp,
                                              unsigned short* T0) {
    int b = blockIdx.x, tid = threadIdx.x;
    if (b < SB) {
        int e0 = b * 256 + tid;
        int e1 = e0 + SSTRIDE, e2 = e0 + 2 * SSTRIDE, e3 = e0 + 3 * SSTRIDE;
        int m0 = mask[e0], m1 = mask[e1], m2 = mask[e2];
        int m3 = (e3 < N_EDGES) ? mask[e3] : 0;
        int d0 = edst[e0], d1 = edst[e1], d2 = edst[e2];
        int d3 = (e3 < N_EDGES) ? edst[e3] : 0;
        int s0 = esrc[e0], s1 = esrc[e1], s2 = esrc[e2];
        int s3 = (e3 < N_EDGES) ? esrc[e3] : 0;
        int z0 = m0 ? z[s0] : 0, z1 = m1 ? z[s1] : 0;
        int z2 = m2 ? z[s2] : 0, z3 = m3 ? z[s3] : 0;
        int q0 = 0, q1 = 0, q2 = 0, q3 = 0;
        if (m0) q0 = atomicAdd(&fill[d0], 1);
        if (m1) q1 = atomicAdd(&fill[d1], 1);
        if (m2) q2 = atomicAdd(&fill[d2], 1);
        if (m3) q3 = atomicAdd(&fill[d3], 1);
        if (m0 && q0 < ELL_CAP) ell[(size_t)d0 * ELL_CAP + q0] = (unsigned)s0 | ((unsigned)z0 << 17);
        if (m1 && q1 < ELL_CAP) ell[(size_t)d1 * ELL_CAP + q1] = (unsigned)s1 | ((unsigned)z1 << 17);
        if (m2 && q2 < ELL_CAP) ell[(size_t)d2 * ELL_CAP + q2] = (unsigned)s2 | ((unsigned)z2 << 17);
        if (m3 && q3 < ELL_CAP) ell[(size_t)d3 * ELL_CAP + q3] = (unsigned)s3 | ((unsigned)z3 << 17);
    } else if (b < SB + 63) {
        // T0 GEMM tile t (0..62): fp32 ztab/W0 -> bf16 in-register -> MFMA
        int t = b - SB;
        int lane = tid & 63, wv = tid >> 6;
        int m = lane & 15, quad = lane >> 4;
        int row = t * 16 + m;
        const float* ar = ztab + (size_t)(row < MAX_Z ? row : 0) * H + quad * 8;
        bf16x8 A[4];
#pragma unroll
        for (int kk = 0; kk < 4; kk++) {
            float4 u  = *(const float4*)(ar + kk * 32);
            float4 v4 = *(const float4*)(ar + kk * 32 + 4);
            bf16x8 aa;
            aa[0] = (short)f2bf(u.x);  aa[1] = (short)f2bf(u.y);
            aa[2] = (short)f2bf(u.z);  aa[3] = (short)f2bf(u.w);
            aa[4] = (short)f2bf(v4.x); aa[5] = (short)f2bf(v4.y);
            aa[6] = (short)f2bf(v4.z); aa[7] = (short)f2bf(v4.w);
            A[kk] = aa;
        }
#pragma unroll
        for (int c2 = 0; c2 < 2; c2++) {
            int c = wv * 2 + c2;
            int n = c * 16 + m;
            f32x4 acc = (f32x4){0.f, 0.f, 0.f, 0.f};
#pragma unroll
            for (int kt = 0; kt < 4; kt++) {
                bf16x8 bb;
#pragma unroll
                for (int j = 0; j < 8; j++)
                    bb[j] = (short)f2bf(W0[(size_t)(kt * 32 + quad * 8 + j) * H + n]);
                acc = __builtin_amdgcn_mfma_f32_16x16x32_bf16(A[kt], bb, acc, 0, 0, 0);
            }
            int r0 = t * 16 + quad * 4;
#pragma unroll
            for (int i2 = 0; i2 < 4; i2++) {
                int r = r0 + i2;
                if (r < MAX_Z) T0[(size_t)r * H + n] = f2bf(acc[i2]);
            }
        }
    } else {
        int bb = b - SB - 63;                          // 0..7: pack W1
        int t = bb * 256 + tid;                        // 0..2047
        int l = t & 63, kt = (t >> 6) & 3, c = t >> 8;
        int quad = l >> 4, n = c * 16 + (l & 15);
        unsigned short o[8];
#pragma unroll
        for (int j = 0; j < 8; j++) o[j] = f2bf(W1[(kt * 32 + quad * 8 + j) * H + n]);
        ushort4 lo = { o[0], o[1], o[2], o[3] }, hi = { o[4], o[5], o[6], o[7] };
        unsigned short* dst = Wp + (size_t)t * 8;
        *(ushort4*)(dst)     = lo;
        *(ushort4*)(dst + 4) = hi;
    }
}

// ---- quad x1 evaluation, packed-z variant --------------------------------
// z for neighbors decoded from the packed list (no z[] gathers); self-row z
// passed in. fill[] gathers remain (deg not final at scan time).
__device__ __forceinline__ void x1_eval4(const unsigned short* __restrict__ T0,
                                         const unsigned* __restrict__ ell,
                                         const int* __restrict__ fill,
                                         int u0, int nt0, int z0,
                                         int u1, int nt1, int z1,
                                         int u2, int nt2, int z2,
                                         int u3, int nt3, int z3,
                                         int lane, int l2, float2 bv,
                                         float& r0x, float& r0y,
                                         float& r1x, float& r1y,
                                         float& r2x, float& r2y,
                                         float& r3x, float& r3y) {
    int li = lane & 31;
    bool hi = lane >= 32;
    int ntA = hi ? nt2 : nt0, ntB = hi ? nt3 : nt1;
    int uA  = hi ? u2 : u0,   uB  = hi ? u3 : u1;
    int nA = ntA > ELL_CAP ? ELL_CAP : ntA;
    int nB = ntB > ELL_CAP ? ELL_CAP : ntB;
    float dvA = rsqrtf(1.f + (float)ntA);
    float dvB = rsqrtf(1.f + (float)ntB);
    unsigned ea = ell[(size_t)uA * ELL_CAP + li];
    unsigned eb = ell[(size_t)uB * ELL_CAP + li];
    int pa = dec_s(ea), pb = dec_s(eb);
    int za = dec_z(ea), zb = dec_z(eb);
    int fa = fill[pa], fb = fill[pb];
    float pca = (li < nA) ? rsqrtf(1.f + (float)fa) * dvA : 0.f;
    float pcb = (li < nB) ? rsqrtf(1.f + (float)fb) * dvB : 0.f;
    float dv0 = rsqrtf(1.f + (float)nt0), dv1 = rsqrtf(1.f + (float)nt1);
    float dv2 = rsqrtf(1.f + (float)nt2), dv3 = rsqrtf(1.f + (float)nt3);
    ushort2 s0 = *(const ushort2*)(T0 + (size_t)z0 * H + l2);
    ushort2 s1 = *(const ushort2*)(T0 + (size_t)z1 * H + l2);
    ushort2 s2 = *(const ushort2*)(T0 + (size_t)z2 * H + l2);
    ushort2 s3 = *(const ushort2*)(T0 + (size_t)z3 * H + l2);
    r0x = dv0 * dv0 * bf2f(s0.x) + bv.x;  r0y = dv0 * dv0 * bf2f(s0.y) + bv.y;
    r1x = dv1 * dv1 * bf2f(s1.x) + bv.x;  r1y = dv1 * dv1 * bf2f(s1.y) + bv.y;
    r2x = dv2 * dv2 * bf2f(s2.x) + bv.x;  r2y = dv2 * dv2 * bf2f(s2.y) + bv.y;
    r3x = dv3 * dv3 * bf2f(s3.x) + bv.x;  r3y = dv3 * dv3 * bf2f(s3.y) + bv.y;
    int n0 = nt0 > ELL_CAP ? ELL_CAP : nt0, n1 = nt1 > ELL_CAP ? ELL_CAP : nt1;
    int n2 = nt2 > ELL_CAP ? ELL_CAP : nt2, n3 = nt3 > ELL_CAP ? ELL_CAP : nt3;
    int kmax = n0 > n1 ? n0 : n1;
    if (n2 > kmax) kmax = n2;
    if (n3 > kmax) kmax = n3;
    int k = 0;
    for (; k + 1 < kmax; k += 2) {
        int zA0 = __shfl(za, k),      zA0b = __shfl(za, k + 1);
        int zC0 = __shfl(za, 32 + k), zC0b = __shfl(za, 32 + k + 1);
        int zB0 = __shfl(zb, k),      zB0b = __shfl(zb, k + 1);
        int zD0 = __shfl(zb, 32 + k), zD0b = __shfl(zb, 32 + k + 1);
        float cA0 = __shfl(pca, k),      cA0b = __shfl(pca, k + 1);
        float cC0 = __shfl(pca, 32 + k), cC0b = __shfl(pca, 32 + k + 1);
        float cB0 = __shfl(pcb, k),      cB0b = __shfl(pcb, k + 1);
        float cD0 = __shfl(pcb, 32 + k), cD0b = __shfl(pcb, 32 + k + 1);
        ushort2 A0  = *(const ushort2*)(T0 + (size_t)zA0  * H + l2);
        ushort2 A0b = *(const ushort2*)(T0 + (size_t)zA0b * H + l2);
        ushort2 B0  = *(const ushort2*)(T0 + (size_t)zB0  * H + l2);
        ushort2 B0b = *(const ushort2*)(T0 + (size_t)zB0b * H + l2);
        ushort2 C0  = *(const ushort2*)(T0 + (size_t)zC0  * H + l2);
        ushort2 C0b = *(const ushort2*)(T0 + (size_t)zC0b * H + l2);
        ushort2 D0  = *(const ushort2*)(T0 + (size_t)zD0  * H + l2);
        ushort2 D0b = *(const ushort2*)(T0 + (size_t)zD0b * H + l2);
        r0x += cA0 * bf2f(A0.x) + cA0b * bf2f(A0b.x);
        r0y += cA0 * bf2f(A0.y) + cA0b * bf2f(A0b.y);
        r1x += cB0 * bf2f(B0.x) + cB0b * bf2f(B0b.x);
        r1y += cB0 * bf2f(B0.y) + cB0b * bf2f(B0b.y);
        r2x += cC0 * bf2f(C0.x) + cC0b * bf2f(C0b.x);
        r2y += cC0 * bf2f(C0.y) + cC0b * bf2f(C0b.y);
        r3x += cD0 * bf2f(D0.x) + cD0b * bf2f(D0b.x);
        r3y += cD0 * bf2f(D0.y) + cD0b * bf2f(D0b.y);
    }
    if (k < kmax) {
        int zA0 = __shfl(za, k), zC0 = __shfl(za, 32 + k);
        int zB0 = __shfl(zb, k), zD0 = __shfl(zb, 32 + k);
        float cA0 = __shfl(pca, k), cC0 = __shfl(pca, 32 + k);
        float cB0 = __shfl(pcb, k), cD0 = __shfl(pcb, 32 + k);
        ushort2 A0 = *(const ushort2*)(T0 + (size_t)zA0 * H + l2);
        ushort2 B0 = *(const ushort2*)(T0 + (size_t)zB0 * H + l2);
        ushort2 C0 = *(const ushort2*)(T0 + (size_t)zC0 * H + l2);
        ushort2 D0 = *(const ushort2*)(T0 + (size_t)zD0 * H + l2);
        r0x += cA0 * bf2f(A0.x); r0y += cA0 * bf2f(A0.y);
        r1x += cB0 * bf2f(B0.x); r1y += cB0 * bf2f(B0.y);
        r2x += cC0 * bf2f(C0.x); r2y += cC0 * bf2f(C0.y);
        r3x += cD0 * bf2f(D0.x); r3y += cD0 * bf2f(D0.y);
    }
    r0x = fmaxf(r0x, 0.f); r0y = fmaxf(r0y, 0.f);
    r1x = fmaxf(r1x, 0.f); r1y = fmaxf(r1y, 0.f);
    r2x = fmaxf(r2x, 0.f); r2y = fmaxf(r2y, 0.f);
    r3x = fmaxf(r3x, 0.f); r3y = fmaxf(r3y, 0.f);
}

// ---- k_ctr: one block per CENTER + fused head (last-arriver per graph) ---
__global__ __launch_bounds__(512) void k_ctr(const int* __restrict__ z,
                                             const unsigned short* __restrict__ T0,
                                             const unsigned* __restrict__ ell,
                                             const int* __restrict__ fill,
                                             const unsigned short* __restrict__ Wp1,
                                             const float* __restrict__ b0,
                                             const float* __restrict__ b1,
                                             const float* __restrict__ W2,
                                             const float* __restrict__ b2,
                                             const float* __restrict__ l1w,
                                             const float* __restrict__ l1b,
                                             const float* __restrict__ l2w,
                                             const float* __restrict__ l2b,
                                             float* __restrict__ x3g,
                                             int* __restrict__ done,
                                             float* __restrict__ out) {
    __shared__ float x2s[SCAPC][132];
    __shared__ unsigned short yt[16][136];
    __shared__ float y2s[128];
    __shared__ float x3s[128];
    __shared__ float ph[128];
    __shared__ float hp[2];
    __shared__ int Sv[SCAPC], Sz[SCAPC], Sn[SCAPC];
    __shared__ float Scoef[SCAPC];
    __shared__ int scnts, n0s, sprev;
    __shared__ float sc0s;

    int bid = blockIdx.x;                    // 0..999
    int tid = threadIdx.x, lane = tid & 63, wv = tid >> 6;   // 8 waves
    int l2 = lane * 2;
    float2 bv = *(const float2*)(b0 + l2);

    // ---- phase 0 (wave 0): S = {c} U nbrs(c); z/deg decoded from list ----
    if (wv == 0) {
        int c = (bid >> 1) * 200 + (bid & 1);
        int ntc = fill[c];
        int nc = ntc > ELL_CAP ? ELL_CAP : ntc;
        float dvc = rsqrtf(1.0f + (float)ntc);
        unsigned e = (lane < nc) ? ell[(size_t)c * ELL_CAP + lane] : 0u;
        int u = dec_s(e), zu = dec_z(e);
        int fu = fill[u];
        if (lane < nc) {
            Sv[1 + lane]    = u;
            Sz[1 + lane]    = zu;
            Sn[1 + lane]    = fu;
            Scoef[1 + lane] = rsqrtf(1.0f + (float)fu) * dvc;
        }
        if (lane == 0) {
            Sv[0] = c; Sz[0] = z[c]; Sn[0] = ntc;
            scnts = 1 + nc; n0s = nc; sc0s = dvc * dvc;
        }
    }
    __syncthreads();
    const int scnt = scnts;

    // ---- phase 1: x2[S] = relu( y1(S) @ W1 + b1 ), tiles of 16 rows ----
    int m = lane & 15, quad = lane >> 4;
    int tiles = (scnt + 15) >> 4;            // <= 3
    for (int t = 0; t < tiles; ++t) {
        for (int q = 0; q < 2; q++) {
            int r = t * 16 + wv * 2 + q;
            float ax = 0.f, ay = 0.f;
            if (r < scnt) {
                int v = Sv[r];
                int zv = Sz[r];
                int ntv = Sn[r];
                int nv = ntv > ELL_CAP ? ELL_CAP : ntv;
                float dv = rsqrtf(1.0f + (float)ntv);
                unsigned e = (lane < ELL_CAP) ? ell[(size_t)v * ELL_CAP + lane] : 0u;
                int px = dec_s(e), zpx = dec_z(e);
                int fx = fill[px];
                float pc = (lane < nv) ? rsqrtf(1.0f + (float)fx) * dv : 0.f;
                {   // call 0: (self, nbr0, nbr1, nbr2)
                    int   u1 = (nv > 0) ? __shfl(px, 0) : v;
                    int   zn1 = (nv > 0) ? __shfl(zpx, 0) : zv;
                    int   f1v = (nv > 0) ? __shfl(fx, 0) : 0;
                    float c1 = (nv > 0) ? __shfl(pc, 0) : 0.f;
                    int   u2 = (nv > 1) ? __shfl(px, 1) : v;
                    int   zn2 = (nv > 1) ? __shfl(zpx, 1) : zv;
                    int   f2v = (nv > 1) ? __shfl(fx, 1) : 0;
                    float c2 = (nv > 1) ? __shfl(pc, 1) : 0.f;
                    int   u3 = (nv > 2) ? __shfl(px, 2) : v;
                    int   zn3 = (nv > 2) ? __shfl(zpx, 2) : zv;
                    int   f3v = (nv > 2) ? __shfl(fx, 2) : 0;
                    float c3 = (nv > 2) ? __shfl(pc, 2) : 0.f;
                    float r0x, r0y, r1x, r1y, r2x, r2y, r3x, r3y;
                    x1_eval4(T0, ell, fill, v, ntv, zv, u1, f1v, zn1,
                             u2, f2v, zn2, u3, f3v, zn3,
                             lane, l2, bv, r0x, r0y, r1x, r1y, r2x, r2y, r3x, r3y);
                    ax = dv * dv * r0x + c1 * r1x + c2 * r2x + c3 * r3x;
                    ay = dv * dv * r0y + c1 * r1y + c2 * r2y + c3 * r3y;
                }
                for (int k = 3; k < nv; k += 4) {
                    int   ka = k;
                    int   kb = (k + 1 < nv) ? k + 1 : k;
                    int   kc = (k + 2 < nv) ? k + 2 : k;
                    int   kd = (k + 3 < nv) ? k + 3 : k;
                    int   ua = __shfl(px, ka), ub = __shfl(px, kb);
                    int   uc = __shfl(px, kc), ud = __shfl(px, kd);
                    int   zna = __shfl(zpx, ka), znb = __shfl(zpx, kb);
                    int   znc = __shfl(zpx, kc), znd = __shfl(zpx, kd);
                    int   fav = __shfl(fx, ka), fbv = __shfl(fx, kb);
                    int   fcv = __shfl(fx, kc), fdv = __shfl(fx, kd);
                    float ca = __shfl(pc, ka);
                    float cb = (k + 1 < nv) ? __shfl(pc, k + 1) : 0.f;
                    float cc = (k + 2 < nv) ? __shfl(pc, k + 2) : 0.f;
                    float cd = (k + 3 < nv) ? __shfl(pc, k + 3) : 0.f;
                    float r0x, r0y, r1x, r1y, r2x, r2y, r3x, r3y;
                    x1_eval4(T0, ell, fill, ua, fav, zna, ub, fbv, znb,
                             uc, fcv, znc, ud, fdv, znd,
                             lane, l2, bv, r0x, r0y, r1x, r1y, r2x, r2y, r3x, r3y);
                    ax += ca * r0x + cb * r1x + cc * r2x + cd * r3x;
                    ay += ca * r0y + cb * r1y + cc * r2y + cd * r3y;
                }
            }
            ushort2 o; o.x = f2bf(ax); o.y = f2bf(ay);
            *(ushort2*)&yt[wv * 2 + q][l2] = o;
        }
        __syncthreads();
        bf16x8 a0 = *(const bf16x8*)&yt[m][quad * 8];
        bf16x8 a1 = *(const bf16x8*)&yt[m][32 + quad * 8];
        bf16x8 a2 = *(const bf16x8*)&yt[m][64 + quad * 8];
        bf16x8 a3 = *(const bf16x8*)&yt[m][96 + quad * 8];
        const unsigned short* bp = Wp1 + ((size_t)(wv * 4) * 64 + lane) * 8;
        bf16x8 b0f = *(const bf16x8*)(bp);
        bf16x8 b1f = *(const bf16x8*)(bp + 512);
        bf16x8 b2f = *(const bf16x8*)(bp + 1024);
        bf16x8 b3f = *(const bf16x8*)(bp + 1536);
        f32x4 a = (f32x4){0.f, 0.f, 0.f, 0.f};
        a = __builtin_amdgcn_mfma_f32_16x16x32_bf16(a0, b0f, a, 0, 0, 0);
        a = __builtin_amdgcn_mfma_f32_16x16x32_bf16(a1, b1f, a, 0, 0, 0);
        a = __builtin_amdgcn_mfma_f32_16x16x32_bf16(a2, b2f, a, 0, 0, 0);
        a = __builtin_amdgcn_mfma_f32_16x16x32_bf16(a3, b3f, a, 0, 0, 0);
        int r0 = t * 16 + quad * 4;
        int col = wv * 16 + m;
        float bb1 = b1[col];
#pragma unroll
        for (int i2 = 0; i2 < 4; i2++) {
            int r = r0 + i2;
            if (r < scnt) x2s[r][col] = fmaxf(a[i2] + bb1, 0.f);
        }
        __syncthreads();
    }

    // ---- phase 2: y2(c) from x2 rows ----
    if (tid < 128) {
        int j = tid;
        float acc = sc0s * x2s[0][j];
        int nc = n0s;
        for (int k = 0; k < nc; k++) acc += Scoef[1 + k] * x2s[1 + k][j];
        y2s[j] = acc;
    }
    __syncthreads();

    // ---- phase 3: x3(c) = y2 @ W2 + b2 -> LDS + global ----
    if (tid < 128) {
        int j = tid;
        float acc = b2[j];
#pragma unroll 4
        for (int k = 0; k < H; k++) acc += y2s[k] * W2[(size_t)k * H + j];
        x3s[j] = acc;
        x3g[(size_t)bid * H + j] = acc;
    }
    __syncthreads();

    // ---- phase 4: fused head — second arriver per graph computes it ----
    // release: our x3g stores drained by __syncthreads; threadfence writes
    // back our XCD L2; ACQ on the fetch_add + threadfence on the winner
    // invalidates its L2 before reading partner's lines (round-2 verified
    // release/acquire pattern; single atomic, no spin).
    if (tid == 0) {
        __threadfence();
        sprev = __hip_atomic_fetch_add(&done[bid >> 1], 1,
                                       __ATOMIC_ACQ_REL, __HIP_MEMORY_SCOPE_AGENT);
    }
    __syncthreads();
    if (sprev == 1) {
        if (tid == 0) __threadfence();
        __syncthreads();
        const float* xp = x3g + (size_t)(bid ^ 1) * H;
        if (tid < 128) ph[tid] = x3s[tid] * xp[tid];
        __syncthreads();
        if (tid < 128) {
            float h = l1b[tid];
#pragma unroll 4
            for (int k = 0; k < H; k++) h += ph[k] * l1w[(size_t)k * H + tid];
            float tv = fmaxf(h, 0.f) * l2w[tid];
#pragma unroll
            for (int d = 32; d > 0; d >>= 1) tv += __shfl_xor(tv, d);
            if (lane == 0) hp[wv] = tv;
        }
        __syncthreads();
        if (tid == 0) out[bid >> 1] = hp[0] + hp[1] + l2b[0];
    }
}

extern "C" void kernel_launch(void* const* d_in, const int* in_sizes, int n_in,
                              void* d_out, int out_size, void* d_ws, size_t ws_size,
                              hipStream_t stream) {
    const int*   z    = (const int*)d_in[0];
    const int*   esrc = (const int*)d_in[1];
    const int*   edst = ((const int*)d_in[1]) + N_EDGES;
    const int*   mask = (const int*)d_in[3];
    const float* ztab = (const float*)d_in[4];
    const float* W0   = (const float*)d_in[5];
    const float* b0   = (const float*)d_in[6];
    const float* W1   = (const float*)d_in[7];
    const float* b1   = (const float*)d_in[8];
    const float* W2   = (const float*)d_in[9];
    const float* b2   = (const float*)d_in[10];
    const float* l1w  = (const float*)d_in[11];
    const float* l1b  = (const float*)d_in[12];
    const float* l2w  = (const float*)d_in[13];
    const float* l2b  = (const float*)d_in[14];
    float* out = (float*)d_out;

    char* w = (char*)d_ws;
    size_t o = 0;
    auto carve = [&](size_t bytes) { char* p = w + o; o = (o + bytes + 255) & ~(size_t)255; return p; };
    int*            fill = (int*)carve((size_t)N_NODES * 4);     // zeroed
    int*            done = (int*)carve((size_t)N_GRAPHS * 4);    // zeroed
    const size_t zero_span = o;
    unsigned*       ell  = (unsigned*)carve((size_t)N_NODES * ELL_CAP * 4);
    unsigned short* Wp   = (unsigned short*)carve((size_t)16384 * 2);   // W1 frags
    unsigned short* T0   = (unsigned short*)carve((size_t)MAX_Z * H * 2);
    float*          x3g  = (float*)carve((size_t)2 * N_GRAPHS * H * 4);

    hipMemsetAsync(d_ws, 0, zero_span, stream);
    // pass 1: packed ELL (src|z<<17) + T0 GEMM + W1 pack
    k_scan<<<SB + 63 + 8, 256, 0, stream>>>(esrc, edst, mask, z, fill, ell,
                                            ztab, W0, W1, Wp, T0);
    // pass 2: per-center back half + fused per-graph head
    k_ctr<<<2 * N_GRAPHS, 512, 0, stream>>>(z, T0, ell, fill, Wp, b0, b1,
                                            W2, b2, l1w, l1b, l2w, l2b,
                                            x3g, done, out);
}

// Round 12
// 158.028 us; speedup vs baseline: 1.2130x; 1.2130x over previous
//
#include <hip/hip_runtime.h>

#define N_NODES 100000
#define N_EDGES 800000
#define H 128
#define MAX_Z 1000
#define N_GRAPHS 500
#define ELL_CAP 32
#define SB 782                   // edge scan blocks: ceil(800000/(256*4))
#define SSTRIDE (SB * 256)       // 200192 threads, 4 edges each
#define SCAPC 33                 // 1 center + 32 neighbor rows

typedef __attribute__((ext_vector_type(8))) short bf16x8;
typedef __attribute__((ext_vector_type(4))) float f32x4;

__device__ __forceinline__ unsigned short f2bf(float f) {
    union { float f; unsigned u; } x; x.f = f;
    unsigned r = x.u + 0x7fffu + ((x.u >> 16) & 1u);   // RTNE
    return (unsigned short)(r >> 16);
}
__device__ __forceinline__ float bf2f(unsigned short u) {
    return __uint_as_float((unsigned)u << 16);
}
// packed ELL entry: src | z[src]<<17  (src<2^17, z<2^10; 5 bits spare)
__device__ __forceinline__ int dec_s(unsigned e) {
    int s = (int)(e & 0x1FFFFu);
    return s < N_NODES ? s : 0;          // poison (0xAA..)-safe
}
__device__ __forceinline__ int dec_z(unsigned e) {
    int zz = (int)((e >> 17) & 0x3FFu);
    return zz < MAX_Z ? zz : 0;
}

// ---- k_scan: packed-ELL build (4-edge ILP) + T0 GEMM + W1 pack -----------
// (round-11 verbatim, absmax 0.0) z[src] gathers hide under the RMW latency.
__global__ __launch_bounds__(256) void k_scan(const int* __restrict__ esrc,
                                              const int* __restrict__ edst,
                                              const int* __restrict__ mask,
                                              const int* __restrict__ z,
                                              int* fill, unsigned* ell,
                                              const float* __restrict__ ztab,
                                              const float* __restrict__ W0,
                                              const float* __restrict__ W1,
                                              unsigned short* Wp,
                                              unsigned short* T0) {
    int b = blockIdx.x, tid = threadIdx.x;
    if (b < SB) {
        int e0 = b * 256 + tid;
        int e1 = e0 + SSTRIDE, e2 = e0 + 2 * SSTRIDE, e3 = e0 + 3 * SSTRIDE;
        int m0 = mask[e0], m1 = mask[e1], m2 = mask[e2];
        int m3 = (e3 < N_EDGES) ? mask[e3] : 0;
        int d0 = edst[e0], d1 = edst[e1], d2 = edst[e2];
        int d3 = (e3 < N_EDGES) ? edst[e3] : 0;
        int s0 = esrc[e0], s1 = esrc[e1], s2 = esrc[e2];
        int s3 = (e3 < N_EDGES) ? esrc[e3] : 0;
        int z0 = m0 ? z[s0] : 0, z1 = m1 ? z[s1] : 0;
        int z2 = m2 ? z[s2] : 0, z3 = m3 ? z[s3] : 0;
        int q0 = 0, q1 = 0, q2 = 0, q3 = 0;
        if (m0) q0 = atomicAdd(&fill[d0], 1);
        if (m1) q1 = atomicAdd(&fill[d1], 1);
        if (m2) q2 = atomicAdd(&fill[d2], 1);
        if (m3) q3 = atomicAdd(&fill[d3], 1);
        if (m0 && q0 < ELL_CAP) ell[(size_t)d0 * ELL_CAP + q0] = (unsigned)s0 | ((unsigned)z0 << 17);
        if (m1 && q1 < ELL_CAP) ell[(size_t)d1 * ELL_CAP + q1] = (unsigned)s1 | ((unsigned)z1 << 17);
        if (m2 && q2 < ELL_CAP) ell[(size_t)d2 * ELL_CAP + q2] = (unsigned)s2 | ((unsigned)z2 << 17);
        if (m3 && q3 < ELL_CAP) ell[(size_t)d3 * ELL_CAP + q3] = (unsigned)s3 | ((unsigned)z3 << 17);
    } else if (b < SB + 63) {
        // T0 GEMM tile t (0..62): fp32 ztab/W0 -> bf16 in-register -> MFMA
        int t = b - SB;
        int lane = tid & 63, wv = tid >> 6;
        int m = lane & 15, quad = lane >> 4;
        int row = t * 16 + m;
        const float* ar = ztab + (size_t)(row < MAX_Z ? row : 0) * H + quad * 8;
        bf16x8 A[4];
#pragma unroll
        for (int kk = 0; kk < 4; kk++) {
            float4 u  = *(const float4*)(ar + kk * 32);
            float4 v4 = *(const float4*)(ar + kk * 32 + 4);
            bf16x8 aa;
            aa[0] = (short)f2bf(u.x);  aa[1] = (short)f2bf(u.y);
            aa[2] = (short)f2bf(u.z);  aa[3] = (short)f2bf(u.w);
            aa[4] = (short)f2bf(v4.x); aa[5] = (short)f2bf(v4.y);
            aa[6] = (short)f2bf(v4.z); aa[7] = (short)f2bf(v4.w);
            A[kk] = aa;
        }
#pragma unroll
        for (int c2 = 0; c2 < 2; c2++) {
            int c = wv * 2 + c2;
            int n = c * 16 + m;
            f32x4 acc = (f32x4){0.f, 0.f, 0.f, 0.f};
#pragma unroll
            for (int kt = 0; kt < 4; kt++) {
                bf16x8 bb;
#pragma unroll
                for (int j = 0; j < 8; j++)
                    bb[j] = (short)f2bf(W0[(size_t)(kt * 32 + quad * 8 + j) * H + n]);
                acc = __builtin_amdgcn_mfma_f32_16x16x32_bf16(A[kt], bb, acc, 0, 0, 0);
            }
            int r0 = t * 16 + quad * 4;
#pragma unroll
            for (int i2 = 0; i2 < 4; i2++) {
                int r = r0 + i2;
                if (r < MAX_Z) T0[(size_t)r * H + n] = f2bf(acc[i2]);
            }
        }
    } else {
        int bb = b - SB - 63;                          // 0..7: pack W1
        int t = bb * 256 + tid;                        // 0..2047
        int l = t & 63, kt = (t >> 6) & 3, c = t >> 8;
        int quad = l >> 4, n = c * 16 + (l & 15);
        unsigned short o[8];
#pragma unroll
        for (int j = 0; j < 8; j++) o[j] = f2bf(W1[(kt * 32 + quad * 8 + j) * H + n]);
        ushort4 lo = { o[0], o[1], o[2], o[3] }, hi = { o[4], o[5], o[6], o[7] };
        unsigned short* dst = Wp + (size_t)t * 8;
        *(ushort4*)(dst)     = lo;
        *(ushort4*)(dst + 4) = hi;
    }
}

// ---- quad x1 evaluation, packed-z variant (round-11, absmax 0.0) ---------
__device__ __forceinline__ void x1_eval4(const unsigned short* __restrict__ T0,
                                         const unsigned* __restrict__ ell,
                                         const int* __restrict__ fill,
                                         int u0, int nt0, int z0,
                                         int u1, int nt1, int z1,
                                         int u2, int nt2, int z2,
                                         int u3, int nt3, int z3,
                                         int lane, int l2, float2 bv,
                                         float& r0x, float& r0y,
                                         float& r1x, float& r1y,
                                         float& r2x, float& r2y,
                                         float& r3x, float& r3y) {
    int li = lane & 31;
    bool hi = lane >= 32;
    int ntA = hi ? nt2 : nt0, ntB = hi ? nt3 : nt1;
    int uA  = hi ? u2 : u0,   uB  = hi ? u3 : u1;
    int nA = ntA > ELL_CAP ? ELL_CAP : ntA;
    int nB = ntB > ELL_CAP ? ELL_CAP : ntB;
    float dvA = rsqrtf(1.f + (float)ntA);
    float dvB = rsqrtf(1.f + (float)ntB);
    unsigned ea = ell[(size_t)uA * ELL_CAP + li];
    unsigned eb = ell[(size_t)uB * ELL_CAP + li];
    int pa = dec_s(ea), pb = dec_s(eb);
    int za = dec_z(ea), zb = dec_z(eb);
    int fa = fill[pa], fb = fill[pb];
    float pca = (li < nA) ? rsqrtf(1.f + (float)fa) * dvA : 0.f;
    float pcb = (li < nB) ? rsqrtf(1.f + (float)fb) * dvB : 0.f;
    float dv0 = rsqrtf(1.f + (float)nt0), dv1 = rsqrtf(1.f + (float)nt1);
    float dv2 = rsqrtf(1.f + (float)nt2), dv3 = rsqrtf(1.f + (float)nt3);
    ushort2 s0 = *(const ushort2*)(T0 + (size_t)z0 * H + l2);
    ushort2 s1 = *(const ushort2*)(T0 + (size_t)z1 * H + l2);
    ushort2 s2 = *(const ushort2*)(T0 + (size_t)z2 * H + l2);
    ushort2 s3 = *(const ushort2*)(T0 + (size_t)z3 * H + l2);
    r0x = dv0 * dv0 * bf2f(s0.x) + bv.x;  r0y = dv0 * dv0 * bf2f(s0.y) + bv.y;
    r1x = dv1 * dv1 * bf2f(s1.x) + bv.x;  r1y = dv1 * dv1 * bf2f(s1.y) + bv.y;
    r2x = dv2 * dv2 * bf2f(s2.x) + bv.x;  r2y = dv2 * dv2 * bf2f(s2.y) + bv.y;
    r3x = dv3 * dv3 * bf2f(s3.x) + bv.x;  r3y = dv3 * dv3 * bf2f(s3.y) + bv.y;
    int n0 = nt0 > ELL_CAP ? ELL_CAP : nt0, n1 = nt1 > ELL_CAP ? ELL_CAP : nt1;
    int n2 = nt2 > ELL_CAP ? ELL_CAP : nt2, n3 = nt3 > ELL_CAP ? ELL_CAP : nt3;
    int kmax = n0 > n1 ? n0 : n1;
    if (n2 > kmax) kmax = n2;
    if (n3 > kmax) kmax = n3;
    int k = 0;
    for (; k + 1 < kmax; k += 2) {
        int zA0 = __shfl(za, k),      zA0b = __shfl(za, k + 1);
        int zC0 = __shfl(za, 32 + k), zC0b = __shfl(za, 32 + k + 1);
        int zB0 = __shfl(zb, k),      zB0b = __shfl(zb, k + 1);
        int zD0 = __shfl(zb, 32 + k), zD0b = __shfl(zb, 32 + k + 1);
        float cA0 = __shfl(pca, k),      cA0b = __shfl(pca, k + 1);
        float cC0 = __shfl(pca, 32 + k), cC0b = __shfl(pca, 32 + k + 1);
        float cB0 = __shfl(pcb, k),      cB0b = __shfl(pcb, k + 1);
        float cD0 = __shfl(pcb, 32 + k), cD0b = __shfl(pcb, 32 + k + 1);
        ushort2 A0  = *(const ushort2*)(T0 + (size_t)zA0  * H + l2);
        ushort2 A0b = *(const ushort2*)(T0 + (size_t)zA0b * H + l2);
        ushort2 B0  = *(const ushort2*)(T0 + (size_t)zB0  * H + l2);
        ushort2 B0b = *(const ushort2*)(T0 + (size_t)zB0b * H + l2);
        ushort2 C0  = *(const ushort2*)(T0 + (size_t)zC0  * H + l2);
        ushort2 C0b = *(const ushort2*)(T0 + (size_t)zC0b * H + l2);
        ushort2 D0  = *(const ushort2*)(T0 + (size_t)zD0  * H + l2);
        ushort2 D0b = *(const ushort2*)(T0 + (size_t)zD0b * H + l2);
        r0x += cA0 * bf2f(A0.x) + cA0b * bf2f(A0b.x);
        r0y += cA0 * bf2f(A0.y) + cA0b * bf2f(A0b.y);
        r1x += cB0 * bf2f(B0.x) + cB0b * bf2f(B0b.x);
        r1y += cB0 * bf2f(B0.y) + cB0b * bf2f(B0b.y);
        r2x += cC0 * bf2f(C0.x) + cC0b * bf2f(C0b.x);
        r2y += cC0 * bf2f(C0.y) + cC0b * bf2f(C0b.y);
        r3x += cD0 * bf2f(D0.x) + cD0b * bf2f(D0b.x);
        r3y += cD0 * bf2f(D0.y) + cD0b * bf2f(D0b.y);
    }
    if (k < kmax) {
        int zA0 = __shfl(za, k), zC0 = __shfl(za, 32 + k);
        int zB0 = __shfl(zb, k), zD0 = __shfl(zb, 32 + k);
        float cA0 = __shfl(pca, k), cC0 = __shfl(pca, 32 + k);
        float cB0 = __shfl(pcb, k), cD0 = __shfl(pcb, 32 + k);
        ushort2 A0 = *(const ushort2*)(T0 + (size_t)zA0 * H + l2);
        ushort2 B0 = *(const ushort2*)(T0 + (size_t)zB0 * H + l2);
        ushort2 C0 = *(const ushort2*)(T0 + (size_t)zC0 * H + l2);
        ushort2 D0 = *(const ushort2*)(T0 + (size_t)zD0 * H + l2);
        r0x += cA0 * bf2f(A0.x); r0y += cA0 * bf2f(A0.y);
        r1x += cB0 * bf2f(B0.x); r1y += cB0 * bf2f(B0.y);
        r2x += cC0 * bf2f(C0.x); r2y += cC0 * bf2f(C0.y);
        r3x += cD0 * bf2f(D0.x); r3y += cD0 * bf2f(D0.y);
    }
    r0x = fmaxf(r0x, 0.f); r0y = fmaxf(r0y, 0.f);
    r1x = fmaxf(r1x, 0.f); r1y = fmaxf(r1y, 0.f);
    r2x = fmaxf(r2x, 0.f); r2y = fmaxf(r2y, 0.f);
    r3x = fmaxf(r3x, 0.f); r3y = fmaxf(r3y, 0.f);
}

// ---- k_ctr: one block per CENTER (round-11 minus fused head) -------------
// Round-11 counters: z-pack cut FETCH 5832->4775MB but the in-kernel head
// (threadfence + acq-rel + cross-XCD read per block) doubled the time.
// Head restored to its own 4us kernel (round-8 proven).
__global__ __launch_bounds__(512) void k_ctr(const int* __restrict__ z,
                                             const unsigned short* __restrict__ T0,
                                             const unsigned* __restrict__ ell,
                                             const int* __restrict__ fill,
                                             const unsigned short* __restrict__ Wp1,
                                             const float* __restrict__ b0,
                                             const float* __restrict__ b1,
                                             const float* __restrict__ W2,
                                             const float* __restrict__ b2,
                                             float* __restrict__ x3g) {
    __shared__ float x2s[SCAPC][132];
    __shared__ unsigned short yt[16][136];
    __shared__ float y2s[128];
    __shared__ int Sv[SCAPC], Sz[SCAPC], Sn[SCAPC];
    __shared__ float Scoef[SCAPC];
    __shared__ int scnts, n0s;
    __shared__ float sc0s;

    int bid = blockIdx.x;                    // 0..999
    int tid = threadIdx.x, lane = tid & 63, wv = tid >> 6;   // 8 waves
    int l2 = lane * 2;
    float2 bv = *(const float2*)(b0 + l2);

    // ---- phase 0 (wave 0): S = {c} U nbrs(c); z/deg decoded from list ----
    if (wv == 0) {
        int c = (bid >> 1) * 200 + (bid & 1);
        int ntc = fill[c];
        int nc = ntc > ELL_CAP ? ELL_CAP : ntc;
        float dvc = rsqrtf(1.0f + (float)ntc);
        unsigned e = (lane < nc) ? ell[(size_t)c * ELL_CAP + lane] : 0u;
        int u = dec_s(e), zu = dec_z(e);
        int fu = fill[u];
        if (lane < nc) {
            Sv[1 + lane]    = u;
            Sz[1 + lane]    = zu;
            Sn[1 + lane]    = fu;
            Scoef[1 + lane] = rsqrtf(1.0f + (float)fu) * dvc;
        }
        if (lane == 0) {
            Sv[0] = c; Sz[0] = z[c]; Sn[0] = ntc;
            scnts = 1 + nc; n0s = nc; sc0s = dvc * dvc;
        }
    }
    __syncthreads();
    const int scnt = scnts;

    // ---- phase 1: x2[S] = relu( y1(S) @ W1 + b1 ), tiles of 16 rows ----
    int m = lane & 15, quad = lane >> 4;
    int tiles = (scnt + 15) >> 4;            // <= 3
    for (int t = 0; t < tiles; ++t) {
        for (int q = 0; q < 2; q++) {
            int r = t * 16 + wv * 2 + q;
            float ax = 0.f, ay = 0.f;
            if (r < scnt) {
                int v = Sv[r];
                int zv = Sz[r];
                int ntv = Sn[r];
                int nv = ntv > ELL_CAP ? ELL_CAP : ntv;
                float dv = rsqrtf(1.0f + (float)ntv);
                unsigned e = (lane < ELL_CAP) ? ell[(size_t)v * ELL_CAP + lane] : 0u;
                int px = dec_s(e), zpx = dec_z(e);
                int fx = fill[px];
                float pc = (lane < nv) ? rsqrtf(1.0f + (float)fx) * dv : 0.f;
                {   // call 0: (self, nbr0, nbr1, nbr2)
                    int   u1 = (nv > 0) ? __shfl(px, 0) : v;
                    int   zn1 = (nv > 0) ? __shfl(zpx, 0) : zv;
                    int   f1v = (nv > 0) ? __shfl(fx, 0) : 0;
                    float c1 = (nv > 0) ? __shfl(pc, 0) : 0.f;
                    int   u2 = (nv > 1) ? __shfl(px, 1) : v;
                    int   zn2 = (nv > 1) ? __shfl(zpx, 1) : zv;
                    int   f2v = (nv > 1) ? __shfl(fx, 1) : 0;
                    float c2 = (nv > 1) ? __shfl(pc, 1) : 0.f;
                    int   u3 = (nv > 2) ? __shfl(px, 2) : v;
                    int   zn3 = (nv > 2) ? __shfl(zpx, 2) : zv;
                    int   f3v = (nv > 2) ? __shfl(fx, 2) : 0;
                    float c3 = (nv > 2) ? __shfl(pc, 2) : 0.f;
                    float r0x, r0y, r1x, r1y, r2x, r2y, r3x, r3y;
                    x1_eval4(T0, ell, fill, v, ntv, zv, u1, f1v, zn1,
                             u2, f2v, zn2, u3, f3v, zn3,
                             lane, l2, bv, r0x, r0y, r1x, r1y, r2x, r2y, r3x, r3y);
                    ax = dv * dv * r0x + c1 * r1x + c2 * r2x + c3 * r3x;
                    ay = dv * dv * r0y + c1 * r1y + c2 * r2y + c3 * r3y;
                }
                for (int k = 3; k < nv; k += 4) {
                    int   ka = k;
                    int   kb = (k + 1 < nv) ? k + 1 : k;
                    int   kc = (k + 2 < nv) ? k + 2 : k;
                    int   kd = (k + 3 < nv) ? k + 3 : k;
                    int   ua = __shfl(px, ka), ub = __shfl(px, kb);
                    int   uc = __shfl(px, kc), ud = __shfl(px, kd);
                    int   zna = __shfl(zpx, ka), znb = __shfl(zpx, kb);
                    int   znc = __shfl(zpx, kc), znd = __shfl(zpx, kd);
                    int   fav = __shfl(fx, ka), fbv = __shfl(fx, kb);
                    int   fcv = __shfl(fx, kc), fdv = __shfl(fx, kd);
                    float ca = __shfl(pc, ka);
                    float cb = (k + 1 < nv) ? __shfl(pc, k + 1) : 0.f;
                    float cc = (k + 2 < nv) ? __shfl(pc, k + 2) : 0.f;
                    float cd = (k + 3 < nv) ? __shfl(pc, k + 3) : 0.f;
                    float r0x, r0y, r1x, r1y, r2x, r2y, r3x, r3y;
                    x1_eval4(T0, ell, fill, ua, fav, zna, ub, fbv, znb,
                             uc, fcv, znc, ud, fdv, znd,
                             lane, l2, bv, r0x, r0y, r1x, r1y, r2x, r2y, r3x, r3y);
                    ax += ca * r0x + cb * r1x + cc * r2x + cd * r3x;
                    ay += ca * r0y + cb * r1y + cc * r2y + cd * r3y;
                }
            }
            ushort2 o; o.x = f2bf(ax); o.y = f2bf(ay);
            *(ushort2*)&yt[wv * 2 + q][l2] = o;
        }
        __syncthreads();
        bf16x8 a0 = *(const bf16x8*)&yt[m][quad * 8];
        bf16x8 a1 = *(const bf16x8*)&yt[m][32 + quad * 8];
        bf16x8 a2 = *(const bf16x8*)&yt[m][64 + quad * 8];
        bf16x8 a3 = *(const bf16x8*)&yt[m][96 + quad * 8];
        const unsigned short* bp = Wp1 + ((size_t)(wv * 4) * 64 + lane) * 8;
        bf16x8 b0f = *(const bf16x8*)(bp);
        bf16x8 b1f = *(const bf16x8*)(bp + 512);
        bf16x8 b2f = *(const bf16x8*)(bp + 1024);
        bf16x8 b3f = *(const bf16x8*)(bp + 1536);
        f32x4 a = (f32x4){0.f, 0.f, 0.f, 0.f};
        a = __builtin_amdgcn_mfma_f32_16x16x32_bf16(a0, b0f, a, 0, 0, 0);
        a = __builtin_amdgcn_mfma_f32_16x16x32_bf16(a1, b1f, a, 0, 0, 0);
        a = __builtin_amdgcn_mfma_f32_16x16x32_bf16(a2, b2f, a, 0, 0, 0);
        a = __builtin_amdgcn_mfma_f32_16x16x32_bf16(a3, b3f, a, 0, 0, 0);
        int r0 = t * 16 + quad * 4;
        int col = wv * 16 + m;
        float bb1 = b1[col];
#pragma unroll
        for (int i2 = 0; i2 < 4; i2++) {
            int r = r0 + i2;
            if (r < scnt) x2s[r][col] = fmaxf(a[i2] + bb1, 0.f);
        }
        __syncthreads();
    }

    // ---- phase 2: y2(c) from x2 rows ----
    if (tid < 128) {
        int j = tid;
        float acc = sc0s * x2s[0][j];
        int nc = n0s;
        for (int k = 0; k < nc; k++) acc += Scoef[1 + k] * x2s[1 + k][j];
        y2s[j] = acc;
    }
    __syncthreads();

    // ---- phase 3: x3(c) = y2 @ W2 + b2 -> global ----
    if (tid < 128) {
        int j = tid;
        float acc = b2[j];
#pragma unroll 4
        for (int k = 0; k < H; k++) acc += y2s[k] * W2[(size_t)k * H + j];
        x3g[(size_t)bid * H + j] = acc;
    }
}

// ---- k_head: hadamard + MLP head, one block per graph (round-8 proven) ---
__global__ __launch_bounds__(128) void k_head(const float* __restrict__ x3g,
                                              const float* __restrict__ l1w,
                                              const float* __restrict__ l1b,
                                              const float* __restrict__ l2w,
                                              const float* __restrict__ l2b,
                                              float* __restrict__ out) {
    __shared__ float p[128];
    __shared__ float hp[2];
    int g = blockIdx.x, tid = threadIdx.x, lane = tid & 63, wv = tid >> 6;
    p[tid] = x3g[(size_t)(2 * g) * H + tid] * x3g[(size_t)(2 * g + 1) * H + tid];
    __syncthreads();
    float h = l1b[tid];
#pragma unroll 4
    for (int k = 0; k < H; k++) h += p[k] * l1w[(size_t)k * H + tid];
    float tv = fmaxf(h, 0.f) * l2w[tid];
#pragma unroll
    for (int d = 32; d > 0; d >>= 1) tv += __shfl_xor(tv, d);
    if (lane == 0) hp[wv] = tv;
    __syncthreads();
    if (tid == 0) out[g] = hp[0] + hp[1] + l2b[0];
}

extern "C" void kernel_launch(void* const* d_in, const int* in_sizes, int n_in,
                              void* d_out, int out_size, void* d_ws, size_t ws_size,
                              hipStream_t stream) {
    const int*   z    = (const int*)d_in[0];
    const int*   esrc = (const int*)d_in[1];
    const int*   edst = ((const int*)d_in[1]) + N_EDGES;
    const int*   mask = (const int*)d_in[3];
    const float* ztab = (const float*)d_in[4];
    const float* W0   = (const float*)d_in[5];
    const float* b0   = (const float*)d_in[6];
    const float* W1   = (const float*)d_in[7];
    const float* b1   = (const float*)d_in[8];
    const float* W2   = (const float*)d_in[9];
    const float* b2   = (const float*)d_in[10];
    const float* l1w  = (const float*)d_in[11];
    const float* l1b  = (const float*)d_in[12];
    const float* l2w  = (const float*)d_in[13];
    const float* l2b  = (const float*)d_in[14];
    float* out = (float*)d_out;

    char* w = (char*)d_ws;
    size_t o = 0;
    auto carve = [&](size_t bytes) { char* p = w + o; o = (o + bytes + 255) & ~(size_t)255; return p; };
    int*            fill = (int*)carve((size_t)N_NODES * 4);     // zeroed
    const size_t zero_span = o;
    unsigned*       ell  = (unsigned*)carve((size_t)N_NODES * ELL_CAP * 4);
    unsigned short* Wp   = (unsigned short*)carve((size_t)16384 * 2);   // W1 frags
    unsigned short* T0   = (unsigned short*)carve((size_t)MAX_Z * H * 2);
    float*          x3g  = (float*)carve((size_t)2 * N_GRAPHS * H * 4);

    hipMemsetAsync(d_ws, 0, zero_span, stream);
    // pass 1: packed ELL (src|z<<17) + T0 GEMM + W1 pack
    k_scan<<<SB + 63 + 8, 256, 0, stream>>>(esrc, edst, mask, z, fill, ell,
                                            ztab, W0, W1, Wp, T0);
    // pass 2: per-center back half -> x3g[1000][128]
    k_ctr<<<2 * N_GRAPHS, 512, 0, stream>>>(z, T0, ell, fill, Wp, b0, b1,
                                            W2, b2, x3g);
    // pass 3: hadamard + MLP head per graph
    k_head<<<N_GRAPHS, 128, 0, stream>>>(x3g, l1w, l1b, l2w, l2b, out);
}

// Round 13
// 150.593 us; speedup vs baseline: 1.2729x; 1.0494x over previous
//
#include <hip/hip_runtime.h>

#define N_NODES 100000
#define N_EDGES 800000
#define H 128
#define MAX_Z 1000
#define N_GRAPHS 500
#define ELL_CAP 32
#define SB 782                   // edge scan blocks: ceil(800000/(256*4))
#define SSTRIDE (SB * 256)       // 200192 threads, 4 edges each
#define SCAP 66                  // 2 centers + 2*32 neighbors

typedef __attribute__((ext_vector_type(8))) short bf16x8;
typedef __attribute__((ext_vector_type(4))) float f32x4;

__device__ __forceinline__ unsigned short f2bf(float f) {
    union { float f; unsigned u; } x; x.f = f;
    unsigned r = x.u + 0x7fffu + ((x.u >> 16) & 1u);   // RTNE
    return (unsigned short)(r >> 16);
}
__device__ __forceinline__ float bf2f(unsigned short u) {
    return __uint_as_float((unsigned)u << 16);
}
__device__ __forceinline__ int clampid(int p) {       // poison (0xAA..) is negative
    return (p < 0 || p >= N_NODES) ? 0 : p;
}

// ---- k_scan: ELL build with 4-edge ILP + T0 GEMM + W1 pack ---------------
__global__ __launch_bounds__(256) void k_scan(const int* __restrict__ esrc,
                                              const int* __restrict__ edst,
                                              const int* __restrict__ mask,
                                              int* fill, int* ell,
                                              const float* __restrict__ ztab,
                                              const float* __restrict__ W0,
                                              const float* __restrict__ W1,
                                              unsigned short* Wp,
                                              unsigned short* T0) {
    int b = blockIdx.x, tid = threadIdx.x;
    if (b < SB) {
        int e0 = b * 256 + tid;
        int e1 = e0 + SSTRIDE, e2 = e0 + 2 * SSTRIDE, e3 = e0 + 3 * SSTRIDE;
        int m0 = mask[e0], m1 = mask[e1], m2 = mask[e2];
        int m3 = (e3 < N_EDGES) ? mask[e3] : 0;
        int d0 = edst[e0], d1 = edst[e1], d2 = edst[e2];
        int d3 = (e3 < N_EDGES) ? edst[e3] : 0;
        int s0 = esrc[e0], s1 = esrc[e1], s2 = esrc[e2];
        int s3 = (e3 < N_EDGES) ? esrc[e3] : 0;
        int q0 = 0, q1 = 0, q2 = 0, q3 = 0;
        if (m0) q0 = atomicAdd(&fill[d0], 1);
        if (m1) q1 = atomicAdd(&fill[d1], 1);
        if (m2) q2 = atomicAdd(&fill[d2], 1);
        if (m3) q3 = atomicAdd(&fill[d3], 1);
        if (m0 && q0 < ELL_CAP) ell[(size_t)d0 * ELL_CAP + q0] = s0;
        if (m1 && q1 < ELL_CAP) ell[(size_t)d1 * ELL_CAP + q1] = s1;
        if (m2 && q2 < ELL_CAP) ell[(size_t)d2 * ELL_CAP + q2] = s2;
        if (m3 && q3 < ELL_CAP) ell[(size_t)d3 * ELL_CAP + q3] = s3;
    } else if (b < SB + 63) {
        // T0 GEMM tile t (0..62): fp32 ztab/W0 -> bf16 in-register -> MFMA
        int t = b - SB;
        int lane = tid & 63, wv = tid >> 6;
        int m = lane & 15, quad = lane >> 4;
        int row = t * 16 + m;
        const float* ar = ztab + (size_t)(row < MAX_Z ? row : 0) * H + quad * 8;
        bf16x8 A[4];
#pragma unroll
        for (int kk = 0; kk < 4; kk++) {
            float4 u  = *(const float4*)(ar + kk * 32);
            float4 v4 = *(const float4*)(ar + kk * 32 + 4);
            bf16x8 aa;
            aa[0] = (short)f2bf(u.x);  aa[1] = (short)f2bf(u.y);
            aa[2] = (short)f2bf(u.z);  aa[3] = (short)f2bf(u.w);
            aa[4] = (short)f2bf(v4.x); aa[5] = (short)f2bf(v4.y);
            aa[6] = (short)f2bf(v4.z); aa[7] = (short)f2bf(v4.w);
            A[kk] = aa;
        }
#pragma unroll
        for (int c2 = 0; c2 < 2; c2++) {
            int c = wv * 2 + c2;
            int n = c * 16 + m;
            f32x4 acc = (f32x4){0.f, 0.f, 0.f, 0.f};
#pragma unroll
            for (int kt = 0; kt < 4; kt++) {
                bf16x8 bb;
#pragma unroll
                for (int j = 0; j < 8; j++)
                    bb[j] = (short)f2bf(W0[(size_t)(kt * 32 + quad * 8 + j) * H + n]);
                acc = __builtin_amdgcn_mfma_f32_16x16x32_bf16(A[kt], bb, acc, 0, 0, 0);
            }
            int r0 = t * 16 + quad * 4;
#pragma unroll
            for (int i2 = 0; i2 < 4; i2++) {
                int r = r0 + i2;
                if (r < MAX_Z) T0[(size_t)r * H + n] = f2bf(acc[i2]);
            }
        }
    } else {
        int bb = b - SB - 63;                          // 0..7: pack W1
        int t = bb * 256 + tid;                        // 0..2047
        int l = t & 63, kt = (t >> 6) & 3, c = t >> 8;
        int quad = l >> 4, n = c * 16 + (l & 15);
        unsigned short o[8];
#pragma unroll
        for (int j = 0; j < 8; j++) o[j] = f2bf(W1[(kt * 32 + quad * 8 + j) * H + n]);
        ushort4 lo = { o[0], o[1], o[2], o[3] }, hi = { o[4], o[5], o[6], o[7] };
        unsigned short* dst = Wp + (size_t)t * 8;
        *(ushort4*)(dst)     = lo;
        *(ushort4*)(dst + 4) = hi;
    }
}

// ---- paired x1 evaluation: two nodes' layer-0 rows, loads interleaved ----
// x1[u] = relu( dv_u^2 * T0[z[u]] + sum_nbr coef * T0[z[nbr]] + b0 )
// lanes >= fill-cursor contribute coef 0 (poison ELL entries clamped to 0).
__device__ __forceinline__ void x1_eval2(const int* __restrict__ z,
                                         const unsigned short* __restrict__ T0,
                                         const int* __restrict__ ell,
                                         const int* __restrict__ fill,
                                         int u0, int nt0, int u1, int nt1,
                                         int lane, int l2, float2 bv,
                                         float& r0x, float& r0y,
                                         float& r1x, float& r1y) {
    int na = nt0 > ELL_CAP ? ELL_CAP : nt0;
    int nb = nt1 > ELL_CAP ? ELL_CAP : nt1;
    float dva = rsqrtf(1.0f + (float)nt0);
    float dvb = rsqrtf(1.0f + (float)nt1);
    int pa = (lane < ELL_CAP) ? ell[(size_t)u0 * ELL_CAP + lane] : 0;
    int pb = (lane < ELL_CAP) ? ell[(size_t)u1 * ELL_CAP + lane] : 0;
    pa = clampid(pa); pb = clampid(pb);
    int za = z[pa], zb = z[pb];
    int fa = fill[pa], fb = fill[pb];
    int zu0 = z[u0], zu1 = z[u1];
    float pca = (lane < na) ? rsqrtf(1.0f + (float)fa) * dva : 0.f;
    float pcb = (lane < nb) ? rsqrtf(1.0f + (float)fb) * dvb : 0.f;
    ushort2 xa = *(const ushort2*)(T0 + (size_t)zu0 * H + l2);
    ushort2 xc = *(const ushort2*)(T0 + (size_t)zu1 * H + l2);
    r0x = dva * dva * bf2f(xa.x) + bv.x;
    r0y = dva * dva * bf2f(xa.y) + bv.y;
    r1x = dvb * dvb * bf2f(xc.x) + bv.x;
    r1y = dvb * dvb * bf2f(xc.y) + bv.y;
    int kmax = na > nb ? na : nb;
    int k = 0;
    for (; k + 1 < kmax; k += 2) {
        int za0 = __shfl(za, k), za1 = __shfl(za, k + 1);
        int zb0 = __shfl(zb, k), zb1 = __shfl(zb, k + 1);
        float ca0 = __shfl(pca, k), ca1 = __shfl(pca, k + 1);
        float cb0 = __shfl(pcb, k), cb1 = __shfl(pcb, k + 1);
        ushort2 A0 = *(const ushort2*)(T0 + (size_t)za0 * H + l2);
        ushort2 A1 = *(const ushort2*)(T0 + (size_t)za1 * H + l2);
        ushort2 B0 = *(const ushort2*)(T0 + (size_t)zb0 * H + l2);
        ushort2 B1 = *(const ushort2*)(T0 + (size_t)zb1 * H + l2);
        r0x += ca0 * bf2f(A0.x) + ca1 * bf2f(A1.x);
        r0y += ca0 * bf2f(A0.y) + ca1 * bf2f(A1.y);
        r1x += cb0 * bf2f(B0.x) + cb1 * bf2f(B1.x);
        r1y += cb0 * bf2f(B0.y) + cb1 * bf2f(B1.y);
    }
    if (k < kmax) {
        int za0 = __shfl(za, k), zb0 = __shfl(zb, k);
        float ca0 = __shfl(pca, k), cb0 = __shfl(pcb, k);
        ushort2 A0 = *(const ushort2*)(T0 + (size_t)za0 * H + l2);
        ushort2 B0 = *(const ushort2*)(T0 + (size_t)zb0 * H + l2);
        r0x += ca0 * bf2f(A0.x); r0y += ca0 * bf2f(A0.y);
        r1x += cb0 * bf2f(B0.x); r1y += cb0 * bf2f(B0.y);
    }
    r0x = fmaxf(r0x, 0.f); r0y = fmaxf(r0y, 0.f);
    r1x = fmaxf(r1x, 0.f); r1y = fmaxf(r1y, 0.f);
}

// ---- k_fused: per-graph full back half ------------------------------------
// S = {c0, c1, nbrs(c0), nbrs(c1)}; x2[S] via on-the-fly x1 recompute + W1
// MFMA; then y2/x3 at the 2 centers (f32 VALU) + hadamard + MLP head.
__global__ __launch_bounds__(512) void k_fused(const int* __restrict__ z,
                                               const unsigned short* __restrict__ T0,
                                               const int* __restrict__ ell,
                                               const int* __restrict__ fill,
                                               const unsigned short* __restrict__ Wp1,
                                               const float* __restrict__ b0,
                                               const float* __restrict__ b1,
                                               const float* __restrict__ W2,
                                               const float* __restrict__ b2,
                                               const float* __restrict__ l1w,
                                               const float* __restrict__ l1b,
                                               const float* __restrict__ l2w,
                                               const float* __restrict__ l2b,
                                               float* __restrict__ out) {
    __shared__ float x2s[SCAP][132];
    __shared__ unsigned short yt[16][136];
    __shared__ float y2s[2][128];
    __shared__ float x3s[2][128];
    __shared__ int Slist[SCAP];
    __shared__ float Scoef[SCAP];
    __shared__ int n0s, n1s, scnts;
    __shared__ float sc0s, sc1s;
    __shared__ float hpart[2];

    int g = blockIdx.x;
    int tid = threadIdx.x, lane = tid & 63, wv = tid >> 6;   // 8 waves
    int l2 = lane * 2;
    int c0 = g * 200;
    float2 bv = *(const float2*)(b0 + l2);

    // ---- phase 0 (wave 0): build S + y2 coefficients ----
    if (wv == 0) {
        int half = lane >> 5, li = lane & 31;
        int c = c0 + half;
        int ntc = fill[c];
        int nc = ntc > ELL_CAP ? ELL_CAP : ntc;
        float dvc = rsqrtf(1.0f + (float)ntc);
        int u = (li < nc) ? ell[(size_t)c * ELL_CAP + li] : 0;
        u = clampid(u);
        int fu = fill[u];
        int n0v = __shfl(nc, 0), n1v = __shfl(nc, 32);
        int base = 2 + (half ? n0v : 0);
        if (li < nc) {
            Slist[base + li] = u;
            Scoef[base + li] = rsqrtf(1.0f + (float)fu) * dvc;
        }
        if (lane == 0)  { Slist[0] = c;  n0s = n0v; sc0s = dvc * dvc; scnts = 2 + n0v + n1v; }
        if (lane == 32) { Slist[1] = c;  n1s = n1v; sc1s = dvc * dvc; }
    }
    __syncthreads();
    const int scnt = scnts;

    // ---- phase 1: x2[S] = relu( y1(S) @ W1 + b1 ), tiles of 16 rows ----
    int m = lane & 15, quad = lane >> 4;
    int tiles = (scnt + 15) >> 4;
    for (int t = 0; t < tiles; ++t) {
        for (int q = 0; q < 2; q++) {
            int r = t * 16 + wv * 2 + q;
            float ax = 0.f, ay = 0.f;
            if (r < scnt) {
                int v = Slist[r];
                int ntv = fill[v];
                int nv = ntv > ELL_CAP ? ELL_CAP : ntv;
                float dv = rsqrtf(1.0f + (float)ntv);
                int px = (lane < ELL_CAP) ? ell[(size_t)v * ELL_CAP + lane] : 0;
                px = clampid(px);
                int fx = fill[px];
                float pc = (lane < nv) ? rsqrtf(1.0f + (float)fx) * dv : 0.f;
                // pair 0: (self, nbr0)
                {
                    int u1 = __shfl(px, 0); int f1v = __shfl(fx, 0);
                    float cu = __shfl(pc, 0);
                    float r0x, r0y, r1x, r1y;
                    x1_eval2(z, T0, ell, fill, v, ntv, u1, f1v,
                             lane, l2, bv, r0x, r0y, r1x, r1y);
                    ax = dv * dv * r0x + cu * r1x;
                    ay = dv * dv * r0y + cu * r1y;
                }
                for (int k = 1; k < nv; k += 2) {
                    int ua = __shfl(px, k);     int fav = __shfl(fx, k);
                    float ca = __shfl(pc, k);
                    int kb = (k + 1 < nv) ? k + 1 : k;     // pad with dup (coef 0 if k+1>=nv)
                    int ub = __shfl(px, kb);    int fbv = __shfl(fx, kb);
                    float cb = (k + 1 < nv) ? __shfl(pc, k + 1) : 0.f;
                    float r0x, r0y, r1x, r1y;
                    x1_eval2(z, T0, ell, fill, ua, fav, ub, fbv,
                             lane, l2, bv, r0x, r0y, r1x, r1y);
                    ax += ca * r0x + cb * r1x;
                    ay += ca * r0y + cb * r1y;
                }
            }
            ushort2 o; o.x = f2bf(ax); o.y = f2bf(ay);
            *(ushort2*)&yt[wv * 2 + q][l2] = o;
        }
        __syncthreads();
        bf16x8 a0 = *(const bf16x8*)&yt[m][quad * 8];
        bf16x8 a1 = *(const bf16x8*)&yt[m][32 + quad * 8];
        bf16x8 a2 = *(const bf16x8*)&yt[m][64 + quad * 8];
        bf16x8 a3 = *(const bf16x8*)&yt[m][96 + quad * 8];
        const unsigned short* bp = Wp1 + ((size_t)(wv * 4) * 64 + lane) * 8;
        bf16x8 b0f = *(const bf16x8*)(bp);
        bf16x8 b1f = *(const bf16x8*)(bp + 512);
        bf16x8 b2f = *(const bf16x8*)(bp + 1024);
        bf16x8 b3f = *(const bf16x8*)(bp + 1536);
        f32x4 a = (f32x4){0.f, 0.f, 0.f, 0.f};
        a = __builtin_amdgcn_mfma_f32_16x16x32_bf16(a0, b0f, a, 0, 0, 0);
        a = __builtin_amdgcn_mfma_f32_16x16x32_bf16(a1, b1f, a, 0, 0, 0);
        a = __builtin_amdgcn_mfma_f32_16x16x32_bf16(a2, b2f, a, 0, 0, 0);
        a = __builtin_amdgcn_mfma_f32_16x16x32_bf16(a3, b3f, a, 0, 0, 0);
        int r0 = t * 16 + quad * 4;
        int col = wv * 16 + m;
        float bb1 = b1[col];
#pragma unroll
        for (int i2 = 0; i2 < 4; i2++) {
            int r = r0 + i2;
            if (r < scnt) x2s[r][col] = fmaxf(a[i2] + bb1, 0.f);
        }
        __syncthreads();
    }

    // ---- phase 2: y2 at centers, x3 = y2 @ W2 + b2 (f32 VALU) ----
    if (tid < 256) {
        int c = tid >> 7, j = tid & 127;
        float acc = (c ? sc1s : sc0s) * x2s[c][j];
        int nc = c ? n1s : n0s;
        int off = 2 + (c ? n0s : 0);
        for (int k = 0; k < nc; k++) acc += Scoef[off + k] * x2s[off + k][j];
        y2s[c][j] = acc;
    }
    __syncthreads();
    if (tid < 256) {
        int c = tid >> 7, j = tid & 127;
        float acc = b2[j];
#pragma unroll 4
        for (int k = 0; k < H; k++) acc += y2s[c][k] * W2[(size_t)k * H + j];
        x3s[c][j] = acc;
    }
    __syncthreads();

    // ---- phase 3: hadamard + MLP head ----
    if (tid < 128) {
        int j = tid;
        float h = l1b[j];
#pragma unroll 4
        for (int k = 0; k < H; k++)
            h += (x3s[0][k] * x3s[1][k]) * l1w[(size_t)k * H + j];
        float tval = fmaxf(h, 0.f) * l2w[j];
#pragma unroll
        for (int d = 32; d > 0; d >>= 1) tval += __shfl_xor(tval, d);
        if (lane == 0) hpart[wv] = tval;
    }
    __syncthreads();
    if (tid == 0) out[g] = hpart[0] + hpart[1] + l2b[0];
}

extern "C" void kernel_launch(void* const* d_in, const int* in_sizes, int n_in,
                              void* d_out, int out_size, void* d_ws, size_t ws_size,
                              hipStream_t stream) {
    const int*   z    = (const int*)d_in[0];
    const int*   esrc = (const int*)d_in[1];
    const int*   edst = ((const int*)d_in[1]) + N_EDGES;
    const int*   mask = (const int*)d_in[3];
    const float* ztab = (const float*)d_in[4];
    const float* W0   = (const float*)d_in[5];
    const float* b0   = (const float*)d_in[6];
    const float* W1   = (const float*)d_in[7];
    const float* b1   = (const float*)d_in[8];
    const float* W2   = (const float*)d_in[9];
    const float* b2   = (const float*)d_in[10];
    const float* l1w  = (const float*)d_in[11];
    const float* l1b  = (const float*)d_in[12];
    const float* l2w  = (const float*)d_in[13];
    const float* l2b  = (const float*)d_in[14];
    float* out = (float*)d_out;

    char* w = (char*)d_ws;
    size_t o = 0;
    auto carve = [&](size_t bytes) { char* p = w + o; o = (o + bytes + 255) & ~(size_t)255; return p; };
    int*            fill = (int*)carve((size_t)N_NODES * 4);     // must be zeroed
    const size_t zero_span = o;
    int*            ell  = (int*)carve((size_t)N_NODES * ELL_CAP * 4);
    unsigned short* Wp   = (unsigned short*)carve((size_t)16384 * 2);   // W1 bf16 frags
    unsigned short* T0   = (unsigned short*)carve((size_t)MAX_Z * H * 2);

    hipMemsetAsync(d_ws, 0, zero_span, stream);
    // pass 1: ELL build (4-edge ILP) + T0 GEMM + W1 pack
    k_scan<<<SB + 63 + 8, 256, 0, stream>>>(esrc, edst, mask, fill, ell,
                                            ztab, W0, W1, Wp, T0);
    // pass 2: everything else, one block per graph
    k_fused<<<N_GRAPHS, 512, 0, stream>>>(z, T0, ell, fill, Wp, b0, b1,
                                          W2, b2, l1w, l1b, l2w, l2b, out);
}